// Round 14
// baseline (1157.748 us; speedup 1.0000x reference)
//
#include <hip/hip_runtime.h>
#include <hip/hip_bf16.h>
#include <math.h>

#define V_N    100000
#define E_N    400000
#define NFEAT  74
#define NEFEAT 12
#define G_DIM  200
#define LDA    224          // padded leading dim for all bf16 node matrices
#define L_N    2
#define NG_N   4000
#define NROWB  391          // cdiv(V_N,256)
#define NROWP  392          // padded to multiple of 8
#define NSWZ   (NROWP / 8 * 56)    // 7-cb swizzled grid = 2744 (gemm)
#define NSWZG  (NROWP / 8 * 112)   // 14-cb swizzled grid = 5488 (gru)

static inline int cdiv(int a, int b) { return (a + b - 1) / b; }

__device__ __forceinline__ float lrelu_f(float x) { return x > 0.f ? x : 0.01f * x; }
// fast transcendentals: v_exp_f32 + v_rcp_f32 (~1 ulp; exact saturation at +-inf)
__device__ __forceinline__ float sigmoid_f(float x)
{
    return __builtin_amdgcn_rcpf(1.f + __expf(-x));
}
__device__ __forceinline__ float tanh_f(float x)
{
    return 1.f - 2.f * __builtin_amdgcn_rcpf(__expf(2.f * x) + 1.f);
}
__device__ __forceinline__ float elu_f(float x) { return x > 0.f ? x : __expf(x) - 1.f; }
__device__ __forceinline__ float bf2f(__hip_bfloat16 x) { return __bfloat162float(x); }
__device__ __forceinline__ float bfbits2f(short s) {
    return __uint_as_float(((unsigned)(unsigned short)s) << 16);
}

__device__ __forceinline__ short f2bf(float f) {
    __hip_bfloat16 b = __float2bfloat16(f);
    short s;
    __builtin_memcpy(&s, &b, 2);
    return s;
}

typedef short short8 __attribute__((ext_vector_type(8)));
typedef short short4v __attribute__((ext_vector_type(4)));
typedef float f32x4 __attribute__((ext_vector_type(4)));

#define MFMA16(a, b, c) __builtin_amdgcn_mfma_f32_16x16x32_bf16((a), (b), (c), 0, 0, 0)

// async global->LDS, 16B per lane; LDS dest = uniform base + lane*16
#define GLOAD_LDS16(gp, lp) \
    __builtin_amdgcn_global_load_lds((const __attribute__((address_space(1))) void*)(gp), \
                                     (__attribute__((address_space(3))) void*)(lp), 16, 0, 0)

#define WAITVM(n) do { \
    asm volatile("s_waitcnt vmcnt(" #n ")" ::: "memory"); \
    __builtin_amdgcn_sched_barrier(0); \
} while (0)

// XCD-aware swizzles: all cb-blocks of one row-tile land on the same XCD (lin%8)
__device__ __forceinline__ void swz_decode7(int lin, int& rowBlk, int& cb)
{
    int grp = lin / 56;
    int rem = lin % 56;
    cb = rem >> 3;            // 0..6
    rowBlk = grp * 8 + (rem & 7);
}

__device__ __forceinline__ void swz_decode14(int lin, int& rowBlk, int& cb)
{
    int grp = lin / 112;
    int rem = lin % 112;
    cb = rem >> 3;            // 0..13
    rowBlk = grp * 8 + (rem & 7);
}

// q = ef @ Wef with Wef slice held in 12 f32x4 VGPRs (static indices only)
__device__ __forceinline__ f32x4 qcalc(const f32x4* wef, f32x4 ef0, f32x4 ef1, f32x4 ef2)
{
    f32x4 q = ef0[0] * wef[0];
    q += ef0[1] * wef[1];
    q += ef0[2] * wef[2];
    q += ef0[3] * wef[3];
    q += ef1[0] * wef[4];
    q += ef1[1] * wef[5];
    q += ef1[2] * wef[6];
    q += ef1[3] * wef[7];
    q += ef2[0] * wef[8];
    q += ef2[1] * wef[9];
    q += ef2[2] * wef[10];
    q += ef2[3] * wef[11];
    return q;
}

// ---------------------------------------------------------------------------
__global__ __launch_bounds__(256)
void fill_kernel(float* __restrict__ p, float v, int n)
{
    int i = blockIdx.x * blockDim.x + threadIdx.x;
    if (i < n) p[i] = v;
}

__global__ __launch_bounds__(256)
void fill_int_kernel(int* __restrict__ p, int v, int n)
{
    int i = blockIdx.x * blockDim.x + threadIdx.x;
    if (i < n) p[i] = v;
}

// zero only the pad columns (k in [200,224)) of the 4 contiguous node matrices
__global__ __launch_bounds__(256)
void pad_zero_kernel(short* __restrict__ base, size_t VP)
{
    int idx = blockIdx.x * blockDim.x + threadIdx.x;
    if (idx >= 4 * V_N) return;
    int mat = idx / V_N, row = idx % V_N;
    short* p = base + (size_t)mat * VP + (long)row * LDA + G_DIM;
    short8 z = {};
    *(short8*)(p) = z;
    *(short8*)(p + 8) = z;
    *(short8*)(p + 16) = z;
}

// ---------------------------------------------------------------------------
// Weight preps
// ---------------------------------------------------------------------------
__global__ __launch_bounds__(256)
void wprep_kernel(const float* __restrict__ W, short* __restrict__ Wp, int K, int Kpad)
{
    int idx = blockIdx.x * 256 + threadIdx.x;
    if (idx >= 256 * Kpad) return;
    int j = idx / Kpad, k = idx % Kpad;
    float v = (j < G_DIM && k < K) ? W[(long)k * G_DIM + j] : 0.f;
    Wp[idx] = f2bf(v);
}

// Tiled for K=224 GEMM: Wp[cb<7][st<7][cc<32][kk<32]
__global__ __launch_bounds__(256)
void wprep_tiled_kernel(const float* __restrict__ W, short* __restrict__ Wp)
{
    int idx = blockIdx.x * 256 + threadIdx.x;
    if (idx >= 7 * 7 * 1024) return;
    int cb = idx / (7 * 1024);
    int r = idx % (7 * 1024);
    int st = r / 1024;
    int r2 = r % 1024;
    int cc = r2 / 32, kk = r2 % 32;
    int col = cb * 32 + cc, k = st * 32 + kk;
    float v = (col < G_DIM && k < G_DIM) ? W[(long)k * G_DIM + col] : 0.f;
    Wp[idx] = f2bf(v);
}

// GRU tiled (16-col blocks): Wp[cb<14][st<14][g<3][cc<16][kk<32]
// st<7 -> Wih (k = st*32+kk), st>=7 -> Whh (k = (st-7)*32+kk)
__global__ __launch_bounds__(256)
void gru_wprep_kernel(const float* __restrict__ Wih, const float* __restrict__ Whh,
                      short* __restrict__ Wp)
{
    int idx = blockIdx.x * 256 + threadIdx.x;
    if (idx >= 14 * 14 * 1536) return;
    int cb = idx / (14 * 1536);
    int r = idx % (14 * 1536);
    int st = r / 1536;
    int r2 = r % 1536;
    int g = r2 / 512;
    int r3 = r2 % 512;
    int cc = r3 / 32, kk = r3 % 32;
    int col = cb * 16 + cc;
    float v = 0.f;
    if (col < G_DIM) {
        if (st < 7) {
            int k = st * 32 + kk;
            if (k < G_DIM) v = Wih[(long)k * (3 * G_DIM) + g * G_DIM + col];
        } else {
            int k = (st - 7) * 32 + kk;
            if (k < G_DIM) v = Whh[(long)k * (3 * G_DIM) + g * G_DIM + col];
        }
    }
    Wp[idx] = f2bf(v);
}

// ---------------------------------------------------------------------------
// CSR build
// ---------------------------------------------------------------------------
__global__ __launch_bounds__(256)
void hist_kernel(const int* __restrict__ dst, int* __restrict__ deg)
{
    int e = blockIdx.x * blockDim.x + threadIdx.x;
    if (e >= E_N) return;
    atomicAdd(&deg[dst[e]], 1);
}

__global__ __launch_bounds__(256)
void scan1_kernel(const int* __restrict__ deg, int* __restrict__ rp, int* __restrict__ bsum)
{
    __shared__ int s[256];
    int tid = threadIdx.x;
    int v = blockIdx.x * 256 + tid;
    int x = (v < V_N) ? deg[v] : 0;
    s[tid] = x;
    __syncthreads();
    for (int off = 1; off < 256; off <<= 1) {
        int t = (tid >= off) ? s[tid - off] : 0;
        __syncthreads();
        s[tid] += t;
        __syncthreads();
    }
    if (v < V_N) rp[v] = s[tid] - x;
    if (tid == 255) bsum[blockIdx.x] = s[255];
}

__global__ void scan2_kernel(int* __restrict__ bsum, int* __restrict__ rp, int nb)
{
    if (threadIdx.x != 0 || blockIdx.x != 0) return;
    int acc = 0;
    for (int b = 0; b < nb; b++) { int t = bsum[b]; bsum[b] = acc; acc += t; }
    rp[V_N] = acc;
}

__global__ __launch_bounds__(256)
void scan3_kernel(int* __restrict__ rp, const int* __restrict__ bsum)
{
    int v = blockIdx.x * 256 + threadIdx.x;
    if (v < V_N) rp[v] += bsum[v >> 8];
}

// CSR fill storing (edge_id, src[edge_id]) pairs: kills the dependent
// e->src load chain in the edge-gather kernels downstream.
__global__ __launch_bounds__(256)
void csr_fill_kernel(const int* __restrict__ dst, const int* __restrict__ src,
                     const int* __restrict__ rp,
                     int* __restrict__ cnt, int2* __restrict__ perm)
{
    int e = blockIdx.x * blockDim.x + threadIdx.x;
    if (e >= E_N) return;
    int d = dst[e];
    int pos = rp[d] + atomicAdd(&cnt[d], 1);
    perm[pos] = make_int2(e, src[e]);
}

// ---------------------------------------------------------------------------
// Dual 64x64 MFMA GEMM for fp32-A (K=74 pad 96): hv AND P in one A pass.
// FUSED: s1[row] += hv[row]·w2 (pe2_W dot) via 16-lane shfl + atomicAdd —
// replaces the separate node_dot2 pass over hv.
// ---------------------------------------------------------------------------
__global__ __launch_bounds__(256)
void gemm_f32a_dual_kernel(const float* __restrict__ Af32,
                           const short* __restrict__ Wp1, const float* __restrict__ b1,
                           const short* __restrict__ Wp2, const float* __restrict__ b2,
                           const float* __restrict__ w2, float* __restrict__ s1o,
                           __hip_bfloat16* __restrict__ C1,
                           __hip_bfloat16* __restrict__ C2)
{
    __shared__ short As[64 * 40];
    __shared__ short Bs1[64 * 40];
    __shared__ short Bs2[64 * 40];
    const int tid = threadIdx.x;
    const int lane = tid & 63;
    const int w = tid >> 6;
    const int quad = lane >> 4;
    const int lm = lane & 15;
    const int rowBase = blockIdx.y * 64;
    const int j0 = blockIdx.x * 64;
    const int arow = tid >> 2;
    const int akc = (tid & 3) * 8;
    const int agrow = rowBase + arow;

    f32x4 acc1[4] = {}, acc2[4] = {};

    for (int k0 = 0; k0 < 96; k0 += 32) {
        short8 av = {};
        if (agrow < V_N) {
            int gk = k0 + akc;
            #pragma unroll
            for (int i = 0; i < 8; i++) {
                int kg = gk + i;
                av[i] = (kg < NFEAT) ? f2bf(Af32[(long)agrow * NFEAT + kg]) : (short)0;
            }
        }
        *(short8*)&As[arow * 40 + akc] = av;
        {
            int col = tid >> 2;
            *(short8*)&Bs1[col * 40 + akc] =
                *(const short8*)(Wp1 + (long)(j0 + col) * 96 + k0 + akc);
            *(short8*)&Bs2[col * 40 + akc] =
                *(const short8*)(Wp2 + (long)(j0 + col) * 96 + k0 + akc);
        }
        __syncthreads();
        short8 a = *(short8*)&As[(w * 16 + lm) * 40 + quad * 8];
        #pragma unroll
        for (int nt = 0; nt < 4; nt++) {
            short8 bb1 = *(short8*)&Bs1[(nt * 16 + lm) * 40 + quad * 8];
            short8 bb2 = *(short8*)&Bs2[(nt * 16 + lm) * 40 + quad * 8];
            acc1[nt] = MFMA16(a, bb1, acc1[nt]);
            acc2[nt] = MFMA16(a, bb2, acc2[nt]);
        }
        __syncthreads();
    }

    // epilogue: row-outer so the 16 lm-lanes (same w,quad,r) reduce the
    // per-row dot partial for this block's 64 columns.
    #pragma unroll
    for (int r = 0; r < 4; r++) {
        int grow = rowBase + w * 16 + quad * 4 + r;   // uniform across lm
        if (grow >= V_N) continue;
        float psum = 0.f;
        #pragma unroll
        for (int nt = 0; nt < 4; nt++) {
            int col = j0 + nt * 16 + lm;
            bool colv = col < G_DIM;
            int colc = colv ? col : 0;
            float v1 = lrelu_f(acc1[nt][r] + b1[colc]);
            float v2 = acc2[nt][r] + b2[colc];
            if (colv) {
                C1[(long)grow * LDA + col] = __float2bfloat16(v1);
                C2[(long)grow * LDA + col] = __float2bfloat16(v2);
            }
            psum += colv ? v1 * w2[col] : 0.f;
        }
        #pragma unroll
        for (int off = 1; off < 16; off <<= 1) psum += __shfl_xor(psum, off, 64);
        if (lm == 0) atomicAdd(&s1o[grow], psum);
    }
}

// ---------------------------------------------------------------------------
// 256x32 MFMA GEMM, bf16 A [V][LDA], K=224, Wp tiled.
// BARRIER-FREE per-wave pipeline: A via global_load_lds into wave-local LDS
// rows, B direct to VGPRs. Unroll-by-2, counted vmcnt.
// ---------------------------------------------------------------------------
template<int EPI>   // 1 = bias only, 3 = elu
__global__ __launch_bounds__(256)
void gemm_bf16a_kernel(const __hip_bfloat16* __restrict__ Abf,
                       const short* __restrict__ Wp,
                       const float* __restrict__ bias,
                       __hip_bfloat16* __restrict__ Cbf)
{
    __shared__ short As[2][256 * 32];
    int rowBlk, cb;
    swz_decode7(blockIdx.x, rowBlk, cb);
    if (rowBlk >= NROWB) return;
    const int tid = threadIdx.x;
    const int lane = tid & 63;
    const int w = tid >> 6;
    const int quad = lane >> 4;
    const int lm = lane & 15;
    const int j0 = cb * 32;
    const int rowBase = rowBlk * 256;

    const short* WpB = Wp + (long)cb * (7 * 1024);
    const short* As_g = (const short*)Abf;
    const long aoff = (long)(rowBase + w * 64 + (lane >> 2)) * LDA + (lane & 3) * 8;
    const int bfrag = lm * 32 + quad * 8;   // per-lane offset within 1KB col block

    auto stageA = [&](int st, int buf) {
        const int kl = st * 32;
        #pragma unroll
        for (int c = 0; c < 4; c++)
            GLOAD_LDS16(As_g + aoff + (long)c * 16 * LDA + kl,
                        &As[buf][(w * 64 + c * 16) * 32]);
    };
    auto loadB = [&](int st, short8 bf[2]) {
        const short* bp = WpB + st * 1024 + bfrag;
        #pragma unroll
        for (int nt = 0; nt < 2; nt++)
            bf[nt] = *(const short8*)(bp + nt * 512);
    };
    auto mfmaStep = [&](int buf, short8 bf[2], f32x4 acc[4][2]) {
        #pragma unroll
        for (int rt = 0; rt < 4; rt++) {
            short8 a = *(short8*)&As[buf][(w * 64 + rt * 16 + lm) * 32 + quad * 8];
            acc[rt][0] = MFMA16(a, bf[0], acc[rt][0]);
            acc[rt][1] = MFMA16(a, bf[1], acc[rt][1]);
        }
    };

    f32x4 acc[4][2] = {};
    short8 bA[2], bB[2];

    stageA(0, 0);
    loadB(0, bA);
    WAITVM(0);

    #pragma unroll 1
    for (int st = 0; st < 7; st += 2) {
        // even step: consume buf0/bA, prefetch st+1 -> buf1/bB
        if (st + 1 < 7) {
            stageA(st + 1, 1);
            loadB(st + 1, bB);
            WAITVM(6);
        } else {
            WAITVM(0);
        }
        mfmaStep(0, bA, acc);
        if (st + 1 < 7) {
            // odd step: consume buf1/bB, prefetch st+2 -> buf0/bA
            if (st + 2 < 7) {
                stageA(st + 2, 0);
                loadB(st + 2, bA);
                WAITVM(6);
            } else {
                WAITVM(0);
            }
            mfmaStep(1, bB, acc);
        }
    }

    #pragma unroll
    for (int nt = 0; nt < 2; nt++) {
        int col = j0 + nt * 16 + lm;
        if (col >= G_DIM) continue;
        float bv = bias[col];
        #pragma unroll
        for (int rt = 0; rt < 4; rt++) {
            #pragma unroll
            for (int r = 0; r < 4; r++) {
                int grow = rowBase + w * 64 + rt * 16 + quad * 4 + r;
                if (grow >= V_N) continue;
                float v = acc[rt][nt][r] + bv;
                if (EPI == 3) v = elu_f(v);
                Cbf[(long)grow * LDA + col] = __float2bfloat16(v);
            }
        }
    }
}

// ---------------------------------------------------------------------------
// Fused MFMA GRU: 256 rows x 16 cols tile (14 cb blocks).
// BARRIER-FREE per-wave pipeline, unroll-by-2, counted vmcnt(7).
// Epilogue: HW transcendentals + FUSED next-layer edge-weight dots
// (s1 += out·wa, s2 += out·wb) via 16-lane shfl + atomicAdd, replacing the
// separate node_dot2 pass. wa==null disables (last layer).
// Wp layout [cb<14][st<14][g<3][cc<16][kk<32].
// ---------------------------------------------------------------------------
__global__ __launch_bounds__(256, 3)
void gru_mfma_kernel(const __hip_bfloat16* __restrict__ xc,
                     const __hip_bfloat16* __restrict__ h,
                     const short* __restrict__ Wp,
                     const float* __restrict__ bih, const float* __restrict__ bhh,
                     const float* __restrict__ wa, const float* __restrict__ wb,
                     float* __restrict__ s1o, float* __restrict__ s2o,
                     __hip_bfloat16* __restrict__ out)
{
    __shared__ short As[2][256 * 32];
    int rowBlk, cb;
    swz_decode14(blockIdx.x, rowBlk, cb);
    if (rowBlk >= NROWB) return;
    const int tid = threadIdx.x;
    const int lane = tid & 63;
    const int w = tid >> 6;
    const int quad = lane >> 4;
    const int lm = lane & 15;
    const int j0 = cb * 16;
    const int rowBase = rowBlk * 256;

    const short* WpB = Wp + (long)cb * (14 * 1536);
    const short* xc_s = (const short*)xc;
    const short* h_s = (const short*)h;
    const long aoff = (long)(rowBase + w * 64 + (lane >> 2)) * LDA + (lane & 3) * 8;
    const int bfrag = lm * 32 + quad * 8;   // per-lane offset within 1KB gate block

    auto stageA = [&](int st, int buf) {
        const short* Ap = (st < 7) ? xc_s : h_s;
        const int kl = (st < 7 ? st : st - 7) * 32;
        #pragma unroll
        for (int c = 0; c < 4; c++)
            GLOAD_LDS16(Ap + aoff + (long)c * 16 * LDA + kl,
                        &As[buf][(w * 64 + c * 16) * 32]);
    };
    auto loadB = [&](int st, short8 bf[3]) {
        const short* bp = WpB + st * 1536 + bfrag;
        #pragma unroll
        for (int g = 0; g < 3; g++)
            bf[g] = *(const short8*)(bp + g * 512);
    };

    f32x4 aR[4] = {}, aZ[4] = {}, aNl[4] = {}, aNh[4] = {};

    auto mfmaStep = [&](int buf, short8 bf[3], bool lowK) {
        #pragma unroll
        for (int rt = 0; rt < 4; rt++) {
            short8 a = *(short8*)&As[buf][(w * 64 + rt * 16 + lm) * 32 + quad * 8];
            aR[rt] = MFMA16(a, bf[0], aR[rt]);
            aZ[rt] = MFMA16(a, bf[1], aZ[rt]);
            if (lowK) aNl[rt] = MFMA16(a, bf[2], aNl[rt]);
            else      aNh[rt] = MFMA16(a, bf[2], aNh[rt]);
        }
    };

    short8 bA[3], bB[3];

    stageA(0, 0);
    loadB(0, bA);
    WAITVM(0);

    #pragma unroll 1
    for (int st = 0; st < 14; st += 2) {
        // even step: consume buf0/bA, prefetch st+1 -> buf1/bB  (st+1<14 always)
        stageA(st + 1, 1);
        loadB(st + 1, bB);
        WAITVM(7);
        mfmaStep(0, bA, st < 7);
        // odd step: consume buf1/bB, prefetch st+2 -> buf0/bA
        if (st + 2 < 14) {
            stageA(st + 2, 0);
            loadB(st + 2, bA);
            WAITVM(7);
        } else {
            WAITVM(0);
        }
        mfmaStep(1, bB, st + 1 < 7);
    }

    // epilogue: all lanes stay active (clamped indices for pad cols) so the
    // 16 lm-lanes can shfl-reduce the per-row dot partials.
    const int col = j0 + lm;
    const bool colv = col < G_DIM;
    const int colc = colv ? col : 0;
    const float b_r = bih[colc] + bhh[colc];
    const float b_z = bih[G_DIM + colc] + bhh[G_DIM + colc];
    const float b_in = bih[2 * G_DIM + colc];
    const float b_hn = bhh[2 * G_DIM + colc];
    const bool doDot = (wa != nullptr);
    const float wav = (doDot && colv) ? wa[col] : 0.f;
    const float wbv = (doDot && colv) ? wb[col] : 0.f;
    #pragma unroll
    for (int rt = 0; rt < 4; rt++) {
        #pragma unroll
        for (int r = 0; r < 4; r++) {
            int grow = rowBase + w * 64 + rt * 16 + quad * 4 + r;  // uniform in lm
            if (grow >= V_N) continue;
            float rr = sigmoid_f(aR[rt][r] + b_r);
            float zz = sigmoid_f(aZ[rt][r] + b_z);
            float nn = tanh_f(aNl[rt][r] + b_in + rr * (aNh[rt][r] + b_hn));
            float hval = bf2f(h[(long)grow * LDA + colc]);
            float o = (1.f - zz) * nn + zz * hval;
            float orl = o > 0.f ? o : 0.f;
            if (colv) out[(long)grow * LDA + col] = __float2bfloat16(orl);
            if (doDot) {
                float p1 = orl * wav;
                float p2 = orl * wbv;
                #pragma unroll
                for (int off = 1; off < 16; off <<= 1) {
                    p1 += __shfl_xor(p1, off, 64);
                    p2 += __shfl_xor(p2, off, 64);
                }
                if (lm == 0) {
                    atomicAdd(&s1o[grow], p1);
                    atomicAdd(&s2o[grow], p2);
                }
            }
        }
    }
}

// ---------------------------------------------------------------------------
// Ctx fused: wave per node, online softmax, wave-uniform scalar metadata loop
// (register-lean — measured best). int2 perm removes the dependent e->src
// load: one s_load_dwordx2 per edge yields both edge id and src node.
// ---------------------------------------------------------------------------
__global__ __launch_bounds__(256)
void ctx_fused_kernel(const __hip_bfloat16* __restrict__ P,
                      const float* __restrict__ efeat,
                      const int2* __restrict__ perm,
                      const int* __restrict__ rp,
                      const float* __restrict__ s1,
                      const float* __restrict__ pe1W,
                      const float* __restrict__ pe2W, const float* __restrict__ pe2b,
                      __hip_bfloat16* __restrict__ hbar)
{
    const int tid = threadIdx.x;
    const int w = tid >> 6, lane = tid & 63;
    const int vlane = (lane < 50) ? lane : 0;
    const int v = __builtin_amdgcn_readfirstlane(blockIdx.x * 4 + w);
    if (v >= V_N) return;
    const int b = __builtin_amdgcn_readfirstlane(rp[v]);
    const int en = __builtin_amdgcn_readfirstlane(rp[v + 1]);
    if (en == b) {
        if (lane < 50) {
            short4v z = {};
            *(short4v*)((short*)hbar + (long)v * LDA + lane * 4) = z;
        }
        return;
    }
    f32x4 wef[12];
    #pragma unroll
    for (int j = 0; j < 12; j++)
        wef[j] = *(const f32x4*)(pe1W + (long)(NFEAT + j) * G_DIM + vlane * 4);
    const f32x4 w2 = *(const f32x4*)(pe2W + G_DIM + vlane * 4);
    const float s1b = s1[v] + pe2b[0];      // wave-uniform

    float m = -INFINITY, ssum = 0.f;
    f32x4 a = {};
    for (int i = b; i < en; i++) {
        const int2 es = perm[i];            // uniform addr -> s_load_dwordx2
        const int e = __builtin_amdgcn_readfirstlane(es.x);
        const int sN = __builtin_amdgcn_readfirstlane(es.y);
        const f32x4 ef0 = *(const f32x4*)(efeat + (long)e * NEFEAT);
        const f32x4 ef1 = *(const f32x4*)(efeat + (long)e * NEFEAT + 4);
        const f32x4 ef2 = *(const f32x4*)(efeat + (long)e * NEFEAT + 8);
        const short4v pv = *(const short4v*)((const short*)P + (long)sN * LDA + vlane * 4);
        const f32x4 q = qcalc(wef, ef0, ef1, ef2);
        f32x4 he;
        #pragma unroll
        for (int u = 0; u < 4; u++) he[u] = lrelu_f(bfbits2f(pv[u]) + q[u]);
        float dot = he[0] * w2[0] + he[1] * w2[1] + he[2] * w2[2] + he[3] * w2[3];
        if (lane >= 50) dot = 0.f;
        #pragma unroll
        for (int off = 32; off > 0; off >>= 1) dot += __shfl_xor(dot, off, 64);
        const float l = lrelu_f(dot + s1b);          // wave-uniform logit
        if (l <= m) {
            const float wgt = __expf(l - m);
            ssum += wgt;
            #pragma unroll
            for (int u = 0; u < 4; u++) a[u] += wgt * he[u];
        } else {
            const float scale = __expf(m - l);       // first iter: exp(-inf)=0
            ssum = ssum * scale + 1.f;
            #pragma unroll
            for (int u = 0; u < 4; u++) a[u] = a[u] * scale + he[u];
            m = l;
        }
    }
    const float inv = __builtin_amdgcn_rcpf(ssum);
    if (lane < 50) {
        short4v o;
        #pragma unroll
        for (int u = 0; u < 4; u++) o[u] = f2bf(a[u] * inv);
        *(short4v*)((short*)hbar + (long)v * LDA + lane * 4) = o;
    }
}

// ---------------------------------------------------------------------------
// GNN softmax+agg: wave per node, single chunked pass with online rescale.
// int2 perm: chunk setup is one coalesced 8B load (no dependent src gather).
// ---------------------------------------------------------------------------
__global__ __launch_bounds__(256)
void gnn_fused_agg_kernel(const __hip_bfloat16* __restrict__ X,
                          const int2* __restrict__ perm,
                          const int* __restrict__ rp,
                          const float* __restrict__ s1, const float* __restrict__ s2,
                          const float* __restrict__ bias,
                          __hip_bfloat16* __restrict__ out)
{
    const int tid = threadIdx.x;
    const int w = tid >> 6, lane = tid & 63;
    const int vlane = (lane < 50) ? lane : 0;
    const int v = __builtin_amdgcn_readfirstlane(blockIdx.x * 4 + w);
    if (v >= V_N) return;
    const int b = __builtin_amdgcn_readfirstlane(rp[v]);
    const int en = __builtin_amdgcn_readfirstlane(rp[v + 1]);
    if (en == b) {
        if (lane < 50) {
            short4v z = {};
            *(short4v*)((short*)out + (long)v * LDA + lane * 4) = z;
        }
        return;
    }
    const float s1v = s1[v] + bias[0];
    float m = -INFINITY, ssum = 0.f;
    f32x4 a = {};
    for (int cb0 = b; cb0 < en; cb0 += 64) {
        int i = cb0 + lane;
        int sL = 0;
        float lv = -INFINITY;
        if (i < en) {
            sL = perm[i].y;                 // coalesced 8B load, no src gather
            lv = lrelu_f(s1v + s2[sL]);
        }
        // chunk max
        float cm = lv;
        #pragma unroll
        for (int off = 32; off > 0; off >>= 1) cm = fmaxf(cm, __shfl_xor(cm, off, 64));
        const float m_new = fmaxf(m, cm);
        const float scale = __expf(m - m_new);   // first chunk: exp(-inf)=0
        ssum *= scale;
        #pragma unroll
        for (int u = 0; u < 4; u++) a[u] *= scale;
        float wgt = (i < en) ? __expf(lv - m_new) : 0.f;
        float ws = wgt;
        #pragma unroll
        for (int off = 32; off > 0; off >>= 1) ws += __shfl_xor(ws, off, 64);
        ssum += ws;
        const int cnt = min(64, en - cb0);
        // gather loop with prefetch
        int sT = __shfl(sL, 0, 64);
        float wT = __shfl(wgt, 0, 64);
        short4v pv = *(const short4v*)((const short*)X + (long)sT * LDA + vlane * 4);
        for (int t = 0; t < cnt; t++) {
            short4v npv;
            float wN;
            if (t + 1 < cnt) {
                int sN = __shfl(sL, t + 1, 64);
                wN = __shfl(wgt, t + 1, 64);
                npv = *(const short4v*)((const short*)X + (long)sN * LDA + vlane * 4);
            }
            #pragma unroll
            for (int u = 0; u < 4; u++)
                a[u] += wT * bfbits2f(pv[u]);
            if (t + 1 < cnt) { pv = npv; wT = wN; }
        }
        m = m_new;
    }
    const float inv = __builtin_amdgcn_rcpf(ssum);
    if (lane < 50) {
        short4v o;
        #pragma unroll
        for (int u = 0; u < 4; u++) o[u] = f2bf(elu_f(a[u] * inv));
        *(short4v*)((short*)out + (long)v * LDA + lane * 4) = o;
    }
}

// ---------------------------------------------------------------------------
// readout
// ---------------------------------------------------------------------------
__global__ __launch_bounds__(256)
void mask_kernel(const float* __restrict__ nfeat, float* __restrict__ mask)
{
    int v = blockIdx.x * blockDim.x + threadIdx.x;
    if (v >= V_N) return;
    const float* row = nfeat + (long)v * NFEAT;
    float s = row[NFEAT - 4] + row[NFEAT - 3] + row[NFEAT - 2] + row[NFEAT - 1];
    float m = s * (1.f - row[0]);
    mask[v] = 1.f / m - 1.f;
}

__global__ __launch_bounds__(256)
void readout_kernel(const __hip_bfloat16* __restrict__ nf, const float* __restrict__ predW,
                    const float* __restrict__ predb, const float* __restrict__ mask,
                    const int* __restrict__ gid, float* __restrict__ out_atom,
                    float* __restrict__ gsum)
{
    int gtid = blockIdx.x * blockDim.x + threadIdx.x;
    int v = gtid >> 6, lane = gtid & 63;
    if (v >= V_N) return;
    int vlane = (lane < 50) ? lane : 0;
    short4v pv = *(const short4v*)((const short*)nf + (long)v * LDA + vlane * 4);
    f32x4 wv = *(const f32x4*)(predW + vlane * 4);
    float acc = 0.f;
    #pragma unroll
    for (int u = 0; u < 4; u++) acc += bfbits2f(pv[u]) * wv[u];
    if (lane >= 50) acc = 0.f;
    for (int off = 32; off > 0; off >>= 1) acc += __shfl_down(acc, off, 64);
    if (lane == 0) {
        float p = acc + predb[0] + mask[v];
        out_atom[v] = p;
        atomicAdd(&gsum[gid[v]], exp10f(-p));
    }
}

__global__ __launch_bounds__(256)
void graph_out_kernel(const float* __restrict__ gsum, float* __restrict__ out_g)
{
    int g = blockIdx.x * blockDim.x + threadIdx.x;
    if (g >= NG_N) return;
    out_g[g] = -log10f(gsum[g]);
}

// ---------------------------------------------------------------------------
extern "C" void kernel_launch(void* const* d_in, const int* in_sizes, int n_in,
                              void* d_out, int out_size, void* d_ws, size_t ws_size,
                              hipStream_t stream)
{
    const float* node_feats = (const float*)d_in[0];
    const float* edge_feats = (const float*)d_in[1];
    const float* pn_W  = (const float*)d_in[2];
    const float* pn_b  = (const float*)d_in[3];
    const float* pe1_W = (const float*)d_in[4];
    const float* pe1_b = (const float*)d_in[5];
    const float* pe2_W = (const float*)d_in[6];
    const float* pe2_b = (const float*)d_in[7];
    const float* et_W  = (const float*)d_in[8];
    const float* et_b  = (const float*)d_in[9];
    const float* gru0_Wih = (const float*)d_in[10];
    const float* gru0_Whh = (const float*)d_in[11];
    const float* gru0_bih = (const float*)d_in[12];
    const float* gru0_bhh = (const float*)d_in[13];
    const float* gnn_pe_W = (const float*)d_in[14];
    const float* gnn_pe_b = (const float*)d_in[15];
    const float* gnn_pn_W = (const float*)d_in[16];
    const float* gnn_pn_b = (const float*)d_in[17];
    const float* gnn_gru_Wih = (const float*)d_in[18];
    const float* gnn_gru_Whh = (const float*)d_in[19];
    const float* gnn_gru_bih = (const float*)d_in[20];
    const float* gnn_gru_bhh = (const float*)d_in[21];
    const float* pred_W = (const float*)d_in[22];
    const float* pred_b = (const float*)d_in[23];
    const int* src = (const int*)d_in[24];
    const int* dst = (const int*)d_in[25];
    const int* gid = (const int*)d_in[26];

    float* out_g = (float*)d_out;
    float* out_atom = out_g + NG_N;

    char* base = (char*)d_ws;
    size_t off = 0;
    auto take = [&](size_t bytes) -> void* {
        void* p = base + off;
        off += (bytes + 255) & ~(size_t)255;
        return p;
    };
    const size_t VP = (size_t)V_N * LDA;
    const size_t WPL = (size_t)14 * 14 * 1536;   // = 301056
    float* mask   = (float*)take((size_t)V_N * 4);
    float* s1     = (float*)take((size_t)V_N * 4);
    float* s2     = (float*)take((size_t)V_N * 4);
    float* gsum   = (float*)take((size_t)NG_N * 4);
    __hip_bfloat16* c    = (__hip_bfloat16*)take(VP * 2);
    __hip_bfloat16* hv   = (__hip_bfloat16*)take(VP * 2);
    __hip_bfloat16* nf_a = (__hip_bfloat16*)take(VP * 2);
    __hip_bfloat16* nf_b = (__hip_bfloat16*)take(VP * 2);
    short* WpGru = (short*)take(3 * WPL * 2);
    short* Wp_pn0 = (short*)take((size_t)256 * 96 * 2);
    short* Wp_pe1 = (short*)take((size_t)256 * 96 * 2);
    short* Wp_et  = (short*)take((size_t)7 * 7 * 1024 * 2);
    short* Wp_pn1 = (short*)take((size_t)7 * 7 * 1024 * 2);
    short* Wp_pn2 = (short*)take((size_t)7 * 7 * 1024 * 2);
    int* deg  = (int*)take((size_t)V_N * 4);
    int* cnt  = (int*)take((size_t)V_N * 4);
    int* rp   = (int*)take((size_t)(V_N + 1) * 4);
    int2* perm = (int2*)take((size_t)E_N * 8);
    int* bsum = (int*)take((size_t)512 * 4);
    __hip_bfloat16* P    = nf_a;  // alias: nf_a written only at GRU0
    __hip_bfloat16* hbar = nf_b;  // alias: nf_b first written as layer-0 GRU output
    __hip_bfloat16* hvp  = hv;    // alias: hv dead after GRU0

    if (off > ws_size) {
        fill_kernel<<<cdiv(out_size, 256), 256, 0, stream>>>((float*)d_out, -12345.f, out_size);
        return;
    }

    const int BLK = 256;
    const int nScanBlocks = cdiv(V_N, 256);
    const dim3 gOld(4, cdiv(V_N, 64));
    const int gAgg = cdiv(V_N, 4);

    // zero only the pad columns of the 4 contiguous node matrices
    pad_zero_kernel<<<cdiv(4 * V_N, BLK), BLK, 0, stream>>>((short*)c, VP);

    // ---- weight prep ----
    gru_wprep_kernel<<<cdiv(14 * 14 * 1536, 256), BLK, 0, stream>>>(gru0_Wih, gru0_Whh, WpGru);
    for (int l = 0; l < L_N; l++)
        gru_wprep_kernel<<<cdiv(14 * 14 * 1536, 256), BLK, 0, stream>>>(
            gnn_gru_Wih + (size_t)l * G_DIM * 3 * G_DIM,
            gnn_gru_Whh + (size_t)l * G_DIM * 3 * G_DIM,
            WpGru + (size_t)(l + 1) * WPL);
    wprep_kernel<<<cdiv(256 * 96, 256), BLK, 0, stream>>>(pn_W, Wp_pn0, NFEAT, 96);
    wprep_kernel<<<cdiv(256 * 96, 256), BLK, 0, stream>>>(pe1_W, Wp_pe1, NFEAT, 96);
    wprep_tiled_kernel<<<cdiv(7 * 7 * 1024, 256), BLK, 0, stream>>>(et_W, Wp_et);
    wprep_tiled_kernel<<<cdiv(7 * 7 * 1024, 256), BLK, 0, stream>>>(gnn_pn_W, Wp_pn1);
    wprep_tiled_kernel<<<cdiv(7 * 7 * 1024, 256), BLK, 0, stream>>>(
        gnn_pn_W + (size_t)G_DIM * G_DIM, Wp_pn2);

    mask_kernel<<<cdiv(V_N, BLK), BLK, 0, stream>>>(node_feats, mask);

    // ---- CSR build (by dst) ----
    fill_int_kernel<<<cdiv(V_N, BLK), BLK, 0, stream>>>(deg, 0, V_N);
    hist_kernel<<<cdiv(E_N, BLK), BLK, 0, stream>>>(dst, deg);
    scan1_kernel<<<nScanBlocks, BLK, 0, stream>>>(deg, rp, bsum);
    scan2_kernel<<<1, 1, 0, stream>>>(bsum, rp, nScanBlocks);
    scan3_kernel<<<nScanBlocks, BLK, 0, stream>>>(rp, bsum);
    fill_int_kernel<<<cdiv(V_N, BLK), BLK, 0, stream>>>(cnt, 0, V_N);
    csr_fill_kernel<<<cdiv(E_N, BLK), BLK, 0, stream>>>(dst, src, rp, cnt, perm);

    // ---- GetContext ----
    fill_kernel<<<cdiv(V_N, BLK), BLK, 0, stream>>>(s1, 0.f, V_N);
    gemm_f32a_dual_kernel<<<gOld, BLK, 0, stream>>>(
        node_feats, Wp_pn0, pn_b, Wp_pe1, pe1_b, pe2_W, s1, hv, P);
    ctx_fused_kernel<<<gAgg, BLK, 0, stream>>>(
        P, edge_feats, perm, rp, s1, pe1_W, pe2_W, pe2_b, hbar);
    gemm_bf16a_kernel<3><<<NSWZ, BLK, 0, stream>>>(hbar, Wp_et, et_b, c);
    // GRU0 fuses the layer-0 edge-weight dots (s1, s2) into its epilogue
    fill_kernel<<<cdiv(V_N, BLK), BLK, 0, stream>>>(s1, 0.f, V_N);
    fill_kernel<<<cdiv(V_N, BLK), BLK, 0, stream>>>(s2, 0.f, V_N);
    gru_mfma_kernel<<<NSWZG, BLK, 0, stream>>>(
        c, hv, WpGru, gru0_bih, gru0_bhh,
        gnn_pe_W, gnn_pe_W + G_DIM, s1, s2, nf_a);

    // ---- GNN layers ----
    __hip_bfloat16* cur = nf_a;
    __hip_bfloat16* nxt = nf_b;
    for (int l = 0; l < L_N; l++) {
        const float* pe_b = gnn_pe_b + l;
        const float* pnB  = gnn_pn_b + (size_t)l * G_DIM;
        const float* bih  = gnn_gru_bih + (size_t)l * 3 * G_DIM;
        const float* bhh  = gnn_gru_bhh + (size_t)l * 3 * G_DIM;
        const short* WpPn = (l == 0) ? Wp_pn1 : Wp_pn2;

        gemm_bf16a_kernel<1><<<NSWZ, BLK, 0, stream>>>(cur, WpPn, pnB, hvp);
        gnn_fused_agg_kernel<<<gAgg, BLK, 0, stream>>>(
            hvp, perm, rp, s1, s2, pe_b, c);
        if (l + 1 < L_N) {
            // next layer's edge-weight dots fused into this GRU's epilogue
            const float* peN = gnn_pe_W + (size_t)(l + 1) * 2 * G_DIM;
            fill_kernel<<<cdiv(V_N, BLK), BLK, 0, stream>>>(s1, 0.f, V_N);
            fill_kernel<<<cdiv(V_N, BLK), BLK, 0, stream>>>(s2, 0.f, V_N);
            gru_mfma_kernel<<<NSWZG, BLK, 0, stream>>>(
                c, cur, WpGru + (size_t)(l + 1) * WPL, bih, bhh,
                peN, peN + G_DIM, s1, s2, nxt);
        } else {
            gru_mfma_kernel<<<NSWZG, BLK, 0, stream>>>(
                c, cur, WpGru + (size_t)(l + 1) * WPL, bih, bhh,
                nullptr, nullptr, nullptr, nullptr, nxt);
        }

        __hip_bfloat16* tmp = cur; cur = nxt; nxt = tmp;
    }

    // ---- readout ----
    fill_kernel<<<cdiv(NG_N, BLK), BLK, 0, stream>>>(gsum, 0.f, NG_N);
    readout_kernel<<<cdiv(V_N * 64, BLK), BLK, 0, stream>>>(
        cur, pred_W, pred_b, mask, gid, out_atom, gsum);
    graph_out_kernel<<<cdiv(NG_N, BLK), BLK, 0, stream>>>(gsum, out_g);
}

// Round 15
// 1110.194 us; speedup vs baseline: 1.0428x; 1.0428x over previous
//
#include <hip/hip_runtime.h>
#include <hip/hip_bf16.h>
#include <math.h>

#define V_N    100000
#define E_N    400000
#define NFEAT  74
#define NEFEAT 12
#define G_DIM  200
#define LDA    224          // padded leading dim for all bf16 node matrices
#define L_N    2
#define NG_N   4000
#define NROWB  391          // cdiv(V_N,256)
#define NROWP  392          // padded to multiple of 8
#define NSWZ   (NROWP / 8 * 56)    // 7-cb swizzled grid = 2744 (gemm)
#define NSWZG  (NROWP / 8 * 112)   // 14-cb swizzled grid = 5488 (gru)

static inline int cdiv(int a, int b) { return (a + b - 1) / b; }

__device__ __forceinline__ float lrelu_f(float x) { return x > 0.f ? x : 0.01f * x; }
// fast transcendentals: v_exp_f32 + v_rcp_f32 (~1 ulp; exact saturation at +-inf)
__device__ __forceinline__ float sigmoid_f(float x)
{
    return __builtin_amdgcn_rcpf(1.f + __expf(-x));
}
__device__ __forceinline__ float tanh_f(float x)
{
    return 1.f - 2.f * __builtin_amdgcn_rcpf(__expf(2.f * x) + 1.f);
}
__device__ __forceinline__ float elu_f(float x) { return x > 0.f ? x : __expf(x) - 1.f; }
__device__ __forceinline__ float bf2f(__hip_bfloat16 x) { return __bfloat162float(x); }
__device__ __forceinline__ float bfbits2f(short s) {
    return __uint_as_float(((unsigned)(unsigned short)s) << 16);
}

__device__ __forceinline__ short f2bf(float f) {
    __hip_bfloat16 b = __float2bfloat16(f);
    short s;
    __builtin_memcpy(&s, &b, 2);
    return s;
}

typedef short short8 __attribute__((ext_vector_type(8)));
typedef short short4v __attribute__((ext_vector_type(4)));
typedef float f32x4 __attribute__((ext_vector_type(4)));

#define MFMA16(a, b, c) __builtin_amdgcn_mfma_f32_16x16x32_bf16((a), (b), (c), 0, 0, 0)

// async global->LDS, 16B per lane; LDS dest = uniform base + lane*16
#define GLOAD_LDS16(gp, lp) \
    __builtin_amdgcn_global_load_lds((const __attribute__((address_space(1))) void*)(gp), \
                                     (__attribute__((address_space(3))) void*)(lp), 16, 0, 0)

#define WAITVM(n) do { \
    asm volatile("s_waitcnt vmcnt(" #n ")" ::: "memory"); \
    __builtin_amdgcn_sched_barrier(0); \
} while (0)

// XCD-aware swizzles: all cb-blocks of one row-tile land on the same XCD (lin%8)
__device__ __forceinline__ void swz_decode7(int lin, int& rowBlk, int& cb)
{
    int grp = lin / 56;
    int rem = lin % 56;
    cb = rem >> 3;            // 0..6
    rowBlk = grp * 8 + (rem & 7);
}

__device__ __forceinline__ void swz_decode14(int lin, int& rowBlk, int& cb)
{
    int grp = lin / 112;
    int rem = lin % 112;
    cb = rem >> 3;            // 0..13
    rowBlk = grp * 8 + (rem & 7);
}

// q = ef @ Wef with Wef slice held in 12 f32x4 VGPRs (static indices only)
__device__ __forceinline__ f32x4 qcalc(const f32x4* wef, f32x4 ef0, f32x4 ef1, f32x4 ef2)
{
    f32x4 q = ef0[0] * wef[0];
    q += ef0[1] * wef[1];
    q += ef0[2] * wef[2];
    q += ef0[3] * wef[3];
    q += ef1[0] * wef[4];
    q += ef1[1] * wef[5];
    q += ef1[2] * wef[6];
    q += ef1[3] * wef[7];
    q += ef2[0] * wef[8];
    q += ef2[1] * wef[9];
    q += ef2[2] * wef[10];
    q += ef2[3] * wef[11];
    return q;
}

// ---------------------------------------------------------------------------
__global__ __launch_bounds__(256)
void fill_kernel(float* __restrict__ p, float v, int n)
{
    int i = blockIdx.x * blockDim.x + threadIdx.x;
    if (i < n) p[i] = v;
}

__global__ __launch_bounds__(256)
void fill_int_kernel(int* __restrict__ p, int v, int n)
{
    int i = blockIdx.x * blockDim.x + threadIdx.x;
    if (i < n) p[i] = v;
}

// zero only the pad columns (k in [200,224)) of the 4 contiguous node matrices
__global__ __launch_bounds__(256)
void pad_zero_kernel(short* __restrict__ base, size_t VP)
{
    int idx = blockIdx.x * blockDim.x + threadIdx.x;
    if (idx >= 4 * V_N) return;
    int mat = idx / V_N, row = idx % V_N;
    short* p = base + (size_t)mat * VP + (long)row * LDA + G_DIM;
    short8 z = {};
    *(short8*)(p) = z;
    *(short8*)(p + 8) = z;
    *(short8*)(p + 16) = z;
}

// ---------------------------------------------------------------------------
// Weight preps
// ---------------------------------------------------------------------------
__global__ __launch_bounds__(256)
void wprep_kernel(const float* __restrict__ W, short* __restrict__ Wp, int K, int Kpad)
{
    int idx = blockIdx.x * 256 + threadIdx.x;
    if (idx >= 256 * Kpad) return;
    int j = idx / Kpad, k = idx % Kpad;
    float v = (j < G_DIM && k < K) ? W[(long)k * G_DIM + j] : 0.f;
    Wp[idx] = f2bf(v);
}

// Tiled for K=224 GEMM: Wp[cb<7][st<7][cc<32][kk<32]
__global__ __launch_bounds__(256)
void wprep_tiled_kernel(const float* __restrict__ W, short* __restrict__ Wp)
{
    int idx = blockIdx.x * 256 + threadIdx.x;
    if (idx >= 7 * 7 * 1024) return;
    int cb = idx / (7 * 1024);
    int r = idx % (7 * 1024);
    int st = r / 1024;
    int r2 = r % 1024;
    int cc = r2 / 32, kk = r2 % 32;
    int col = cb * 32 + cc, k = st * 32 + kk;
    float v = (col < G_DIM && k < G_DIM) ? W[(long)k * G_DIM + col] : 0.f;
    Wp[idx] = f2bf(v);
}

// GRU tiled (16-col blocks): Wp[cb<14][st<14][g<3][cc<16][kk<32]
// st<7 -> Wih (k = st*32+kk), st>=7 -> Whh (k = (st-7)*32+kk)
__global__ __launch_bounds__(256)
void gru_wprep_kernel(const float* __restrict__ Wih, const float* __restrict__ Whh,
                      short* __restrict__ Wp)
{
    int idx = blockIdx.x * 256 + threadIdx.x;
    if (idx >= 14 * 14 * 1536) return;
    int cb = idx / (14 * 1536);
    int r = idx % (14 * 1536);
    int st = r / 1536;
    int r2 = r % 1536;
    int g = r2 / 512;
    int r3 = r2 % 512;
    int cc = r3 / 32, kk = r3 % 32;
    int col = cb * 16 + cc;
    float v = 0.f;
    if (col < G_DIM) {
        if (st < 7) {
            int k = st * 32 + kk;
            if (k < G_DIM) v = Wih[(long)k * (3 * G_DIM) + g * G_DIM + col];
        } else {
            int k = (st - 7) * 32 + kk;
            if (k < G_DIM) v = Whh[(long)k * (3 * G_DIM) + g * G_DIM + col];
        }
    }
    Wp[idx] = f2bf(v);
}

// ---------------------------------------------------------------------------
// CSR build
// ---------------------------------------------------------------------------
__global__ __launch_bounds__(256)
void hist_kernel(const int* __restrict__ dst, int* __restrict__ deg)
{
    int e = blockIdx.x * blockDim.x + threadIdx.x;
    if (e >= E_N) return;
    atomicAdd(&deg[dst[e]], 1);
}

__global__ __launch_bounds__(256)
void scan1_kernel(const int* __restrict__ deg, int* __restrict__ rp, int* __restrict__ bsum)
{
    __shared__ int s[256];
    int tid = threadIdx.x;
    int v = blockIdx.x * 256 + tid;
    int x = (v < V_N) ? deg[v] : 0;
    s[tid] = x;
    __syncthreads();
    for (int off = 1; off < 256; off <<= 1) {
        int t = (tid >= off) ? s[tid - off] : 0;
        __syncthreads();
        s[tid] += t;
        __syncthreads();
    }
    if (v < V_N) rp[v] = s[tid] - x;
    if (tid == 255) bsum[blockIdx.x] = s[255];
}

__global__ void scan2_kernel(int* __restrict__ bsum, int* __restrict__ rp, int nb)
{
    if (threadIdx.x != 0 || blockIdx.x != 0) return;
    int acc = 0;
    for (int b = 0; b < nb; b++) { int t = bsum[b]; bsum[b] = acc; acc += t; }
    rp[V_N] = acc;
}

__global__ __launch_bounds__(256)
void scan3_kernel(int* __restrict__ rp, const int* __restrict__ bsum)
{
    int v = blockIdx.x * 256 + threadIdx.x;
    if (v < V_N) rp[v] += bsum[v >> 8];
}

// CSR fill storing (edge_id, src[edge_id]) pairs: kills the dependent
// e->src load chain in the edge-gather kernels downstream.
__global__ __launch_bounds__(256)
void csr_fill_kernel(const int* __restrict__ dst, const int* __restrict__ src,
                     const int* __restrict__ rp,
                     int* __restrict__ cnt, int2* __restrict__ perm)
{
    int e = blockIdx.x * blockDim.x + threadIdx.x;
    if (e >= E_N) return;
    int d = dst[e];
    int pos = rp[d] + atomicAdd(&cnt[d], 1);
    perm[pos] = make_int2(e, src[e]);
}

// ---------------------------------------------------------------------------
// Dual 64x64 MFMA GEMM for fp32-A (K=74 pad 96): hv AND P in one A pass
// ---------------------------------------------------------------------------
__global__ __launch_bounds__(256)
void gemm_f32a_dual_kernel(const float* __restrict__ Af32,
                           const short* __restrict__ Wp1, const float* __restrict__ b1,
                           const short* __restrict__ Wp2, const float* __restrict__ b2,
                           __hip_bfloat16* __restrict__ C1,
                           __hip_bfloat16* __restrict__ C2)
{
    __shared__ short As[64 * 40];
    __shared__ short Bs1[64 * 40];
    __shared__ short Bs2[64 * 40];
    const int tid = threadIdx.x;
    const int lane = tid & 63;
    const int w = tid >> 6;
    const int quad = lane >> 4;
    const int lm = lane & 15;
    const int rowBase = blockIdx.y * 64;
    const int j0 = blockIdx.x * 64;
    const int arow = tid >> 2;
    const int akc = (tid & 3) * 8;
    const int agrow = rowBase + arow;

    f32x4 acc1[4] = {}, acc2[4] = {};

    for (int k0 = 0; k0 < 96; k0 += 32) {
        short8 av = {};
        if (agrow < V_N) {
            int gk = k0 + akc;
            #pragma unroll
            for (int i = 0; i < 8; i++) {
                int kg = gk + i;
                av[i] = (kg < NFEAT) ? f2bf(Af32[(long)agrow * NFEAT + kg]) : (short)0;
            }
        }
        *(short8*)&As[arow * 40 + akc] = av;
        {
            int col = tid >> 2;
            *(short8*)&Bs1[col * 40 + akc] =
                *(const short8*)(Wp1 + (long)(j0 + col) * 96 + k0 + akc);
            *(short8*)&Bs2[col * 40 + akc] =
                *(const short8*)(Wp2 + (long)(j0 + col) * 96 + k0 + akc);
        }
        __syncthreads();
        short8 a = *(short8*)&As[(w * 16 + lm) * 40 + quad * 8];
        #pragma unroll
        for (int nt = 0; nt < 4; nt++) {
            short8 bb1 = *(short8*)&Bs1[(nt * 16 + lm) * 40 + quad * 8];
            short8 bb2 = *(short8*)&Bs2[(nt * 16 + lm) * 40 + quad * 8];
            acc1[nt] = MFMA16(a, bb1, acc1[nt]);
            acc2[nt] = MFMA16(a, bb2, acc2[nt]);
        }
        __syncthreads();
    }

    #pragma unroll
    for (int nt = 0; nt < 4; nt++) {
        int col = j0 + nt * 16 + lm;
        if (col >= G_DIM) continue;
        float bv1 = b1[col], bv2 = b2[col];
        #pragma unroll
        for (int r = 0; r < 4; r++) {
            int grow = rowBase + w * 16 + quad * 4 + r;
            if (grow >= V_N) continue;
            C1[(long)grow * LDA + col] = __float2bfloat16(lrelu_f(acc1[nt][r] + bv1));
            C2[(long)grow * LDA + col] = __float2bfloat16(acc2[nt][r] + bv2);
        }
    }
}

// ---------------------------------------------------------------------------
// 256x32 MFMA GEMM, bf16 A [V][LDA], K=224, Wp tiled.
// BARRIER-FREE per-wave pipeline: A via global_load_lds into wave-local LDS
// rows, B direct to VGPRs. Unroll-by-2, counted vmcnt.
// ---------------------------------------------------------------------------
template<int EPI>   // 1 = bias only, 3 = elu
__global__ __launch_bounds__(256)
void gemm_bf16a_kernel(const __hip_bfloat16* __restrict__ Abf,
                       const short* __restrict__ Wp,
                       const float* __restrict__ bias,
                       __hip_bfloat16* __restrict__ Cbf)
{
    __shared__ short As[2][256 * 32];
    int rowBlk, cb;
    swz_decode7(blockIdx.x, rowBlk, cb);
    if (rowBlk >= NROWB) return;
    const int tid = threadIdx.x;
    const int lane = tid & 63;
    const int w = tid >> 6;
    const int quad = lane >> 4;
    const int lm = lane & 15;
    const int j0 = cb * 32;
    const int rowBase = rowBlk * 256;

    const short* WpB = Wp + (long)cb * (7 * 1024);
    const short* As_g = (const short*)Abf;
    const long aoff = (long)(rowBase + w * 64 + (lane >> 2)) * LDA + (lane & 3) * 8;
    const int bfrag = lm * 32 + quad * 8;   // per-lane offset within 1KB col block

    auto stageA = [&](int st, int buf) {
        const int kl = st * 32;
        #pragma unroll
        for (int c = 0; c < 4; c++)
            GLOAD_LDS16(As_g + aoff + (long)c * 16 * LDA + kl,
                        &As[buf][(w * 64 + c * 16) * 32]);
    };
    auto loadB = [&](int st, short8 bf[2]) {
        const short* bp = WpB + st * 1024 + bfrag;
        #pragma unroll
        for (int nt = 0; nt < 2; nt++)
            bf[nt] = *(const short8*)(bp + nt * 512);
    };
    auto mfmaStep = [&](int buf, short8 bf[2], f32x4 acc[4][2]) {
        #pragma unroll
        for (int rt = 0; rt < 4; rt++) {
            short8 a = *(short8*)&As[buf][(w * 64 + rt * 16 + lm) * 32 + quad * 8];
            acc[rt][0] = MFMA16(a, bf[0], acc[rt][0]);
            acc[rt][1] = MFMA16(a, bf[1], acc[rt][1]);
        }
    };

    f32x4 acc[4][2] = {};
    short8 bA[2], bB[2];

    stageA(0, 0);
    loadB(0, bA);
    WAITVM(0);

    #pragma unroll 1
    for (int st = 0; st < 7; st += 2) {
        // even step: consume buf0/bA, prefetch st+1 -> buf1/bB
        if (st + 1 < 7) {
            stageA(st + 1, 1);
            loadB(st + 1, bB);
            WAITVM(6);
        } else {
            WAITVM(0);
        }
        mfmaStep(0, bA, acc);
        if (st + 1 < 7) {
            // odd step: consume buf1/bB, prefetch st+2 -> buf0/bA
            if (st + 2 < 7) {
                stageA(st + 2, 0);
                loadB(st + 2, bA);
                WAITVM(6);
            } else {
                WAITVM(0);
            }
            mfmaStep(1, bB, acc);
        }
    }

    #pragma unroll
    for (int nt = 0; nt < 2; nt++) {
        int col = j0 + nt * 16 + lm;
        if (col >= G_DIM) continue;
        float bv = bias[col];
        #pragma unroll
        for (int rt = 0; rt < 4; rt++) {
            #pragma unroll
            for (int r = 0; r < 4; r++) {
                int grow = rowBase + w * 64 + rt * 16 + quad * 4 + r;
                if (grow >= V_N) continue;
                float v = acc[rt][nt][r] + bv;
                if (EPI == 3) v = elu_f(v);
                Cbf[(long)grow * LDA + col] = __float2bfloat16(v);
            }
        }
    }
}

// ---------------------------------------------------------------------------
// Fused MFMA GRU: 256 rows x 16 cols tile (14 cb blocks).
// BARRIER-FREE per-wave pipeline, unroll-by-2, counted vmcnt(7).
// Epilogue uses HW transcendentals.
// Wp layout [cb<14][st<14][g<3][cc<16][kk<32].
// ---------------------------------------------------------------------------
__global__ __launch_bounds__(256, 3)
void gru_mfma_kernel(const __hip_bfloat16* __restrict__ xc,
                     const __hip_bfloat16* __restrict__ h,
                     const short* __restrict__ Wp,
                     const float* __restrict__ bih, const float* __restrict__ bhh,
                     __hip_bfloat16* __restrict__ out)
{
    __shared__ short As[2][256 * 32];
    int rowBlk, cb;
    swz_decode14(blockIdx.x, rowBlk, cb);
    if (rowBlk >= NROWB) return;
    const int tid = threadIdx.x;
    const int lane = tid & 63;
    const int w = tid >> 6;
    const int quad = lane >> 4;
    const int lm = lane & 15;
    const int j0 = cb * 16;
    const int rowBase = rowBlk * 256;

    const short* WpB = Wp + (long)cb * (14 * 1536);
    const short* xc_s = (const short*)xc;
    const short* h_s = (const short*)h;
    const long aoff = (long)(rowBase + w * 64 + (lane >> 2)) * LDA + (lane & 3) * 8;
    const int bfrag = lm * 32 + quad * 8;   // per-lane offset within 1KB gate block

    auto stageA = [&](int st, int buf) {
        const short* Ap = (st < 7) ? xc_s : h_s;
        const int kl = (st < 7 ? st : st - 7) * 32;
        #pragma unroll
        for (int c = 0; c < 4; c++)
            GLOAD_LDS16(Ap + aoff + (long)c * 16 * LDA + kl,
                        &As[buf][(w * 64 + c * 16) * 32]);
    };
    auto loadB = [&](int st, short8 bf[3]) {
        const short* bp = WpB + st * 1536 + bfrag;
        #pragma unroll
        for (int g = 0; g < 3; g++)
            bf[g] = *(const short8*)(bp + g * 512);
    };

    f32x4 aR[4] = {}, aZ[4] = {}, aNl[4] = {}, aNh[4] = {};

    auto mfmaStep = [&](int buf, short8 bf[3], bool lowK) {
        #pragma unroll
        for (int rt = 0; rt < 4; rt++) {
            short8 a = *(short8*)&As[buf][(w * 64 + rt * 16 + lm) * 32 + quad * 8];
            aR[rt] = MFMA16(a, bf[0], aR[rt]);
            aZ[rt] = MFMA16(a, bf[1], aZ[rt]);
            if (lowK) aNl[rt] = MFMA16(a, bf[2], aNl[rt]);
            else      aNh[rt] = MFMA16(a, bf[2], aNh[rt]);
        }
    };

    short8 bA[3], bB[3];

    stageA(0, 0);
    loadB(0, bA);
    WAITVM(0);

    #pragma unroll 1
    for (int st = 0; st < 14; st += 2) {
        // even step: consume buf0/bA, prefetch st+1 -> buf1/bB  (st+1<14 always)
        stageA(st + 1, 1);
        loadB(st + 1, bB);
        WAITVM(7);
        mfmaStep(0, bA, st < 7);
        // odd step: consume buf1/bB, prefetch st+2 -> buf0/bA
        if (st + 2 < 14) {
            stageA(st + 2, 0);
            loadB(st + 2, bA);
            WAITVM(7);
        } else {
            WAITVM(0);
        }
        mfmaStep(1, bB, st + 1 < 7);
    }

    int col = j0 + lm;
    if (col < G_DIM) {
        // pre-combined gate biases: r/z use bih+bhh; n keeps them separate
        float b_r = bih[col] + bhh[col];
        float b_z = bih[G_DIM + col] + bhh[G_DIM + col];
        float b_in = bih[2 * G_DIM + col];
        float b_hn = bhh[2 * G_DIM + col];
        #pragma unroll
        for (int rt = 0; rt < 4; rt++) {
            #pragma unroll
            for (int r = 0; r < 4; r++) {
                int grow = rowBase + w * 64 + rt * 16 + quad * 4 + r;
                if (grow >= V_N) continue;
                float rr = sigmoid_f(aR[rt][r] + b_r);
                float zz = sigmoid_f(aZ[rt][r] + b_z);
                float nn = tanh_f(aNl[rt][r] + b_in + rr * (aNh[rt][r] + b_hn));
                float hval = bf2f(h[(long)grow * LDA + col]);
                float o = (1.f - zz) * nn + zz * hval;
                out[(long)grow * LDA + col] = __float2bfloat16(o > 0.f ? o : 0.f);
            }
        }
    }
}

// ---------------------------------------------------------------------------
// Node dot(s): s1[v] = X[v]·wa (+ s2[v] = X[v]·wb). Wave per node, vectorized.
// ---------------------------------------------------------------------------
__global__ __launch_bounds__(256)
void node_dot2_kernel(const __hip_bfloat16* __restrict__ X,
                      const float* __restrict__ wa, const float* __restrict__ wb,
                      float* __restrict__ s1, float* __restrict__ s2)
{
    int w = threadIdx.x >> 6, lane = threadIdx.x & 63;
    int v = blockIdx.x * 4 + w;
    if (v >= V_N) return;
    int vlane = (lane < 50) ? lane : 0;
    short4v pv = *(const short4v*)((const short*)X + (long)v * LDA + vlane * 4);
    f32x4 wav = *(const f32x4*)(wa + vlane * 4);
    float a = 0.f, b = 0.f;
    #pragma unroll
    for (int u = 0; u < 4; u++) a += bfbits2f(pv[u]) * wav[u];
    if (wb) {
        f32x4 wbv = *(const f32x4*)(wb + vlane * 4);
        #pragma unroll
        for (int u = 0; u < 4; u++) b += bfbits2f(pv[u]) * wbv[u];
    }
    if (lane >= 50) { a = 0.f; b = 0.f; }
    for (int off = 32; off > 0; off >>= 1) {
        a += __shfl_down(a, off, 64);
        if (wb) b += __shfl_down(b, off, 64);
    }
    if (lane == 0) {
        s1[v] = a;
        if (wb) s2[v] = b;
    }
}

// ---------------------------------------------------------------------------
// Ctx fused: wave per node, online softmax, wave-uniform scalar metadata loop
// (register-lean — measured best). int2 perm removes the dependent e->src
// load: one s_load_dwordx2 per edge yields both edge id and src node.
// ---------------------------------------------------------------------------
__global__ __launch_bounds__(256)
void ctx_fused_kernel(const __hip_bfloat16* __restrict__ P,
                      const float* __restrict__ efeat,
                      const int2* __restrict__ perm,
                      const int* __restrict__ rp,
                      const float* __restrict__ s1,
                      const float* __restrict__ pe1W,
                      const float* __restrict__ pe2W, const float* __restrict__ pe2b,
                      __hip_bfloat16* __restrict__ hbar)
{
    const int tid = threadIdx.x;
    const int w = tid >> 6, lane = tid & 63;
    const int vlane = (lane < 50) ? lane : 0;
    const int v = __builtin_amdgcn_readfirstlane(blockIdx.x * 4 + w);
    if (v >= V_N) return;
    const int b = __builtin_amdgcn_readfirstlane(rp[v]);
    const int en = __builtin_amdgcn_readfirstlane(rp[v + 1]);
    if (en == b) {
        if (lane < 50) {
            short4v z = {};
            *(short4v*)((short*)hbar + (long)v * LDA + lane * 4) = z;
        }
        return;
    }
    f32x4 wef[12];
    #pragma unroll
    for (int j = 0; j < 12; j++)
        wef[j] = *(const f32x4*)(pe1W + (long)(NFEAT + j) * G_DIM + vlane * 4);
    const f32x4 w2 = *(const f32x4*)(pe2W + G_DIM + vlane * 4);
    const float s1b = s1[v] + pe2b[0];      // wave-uniform

    float m = -INFINITY, ssum = 0.f;
    f32x4 a = {};
    for (int i = b; i < en; i++) {
        const int2 es = perm[i];            // uniform addr -> s_load_dwordx2
        const int e = __builtin_amdgcn_readfirstlane(es.x);
        const int sN = __builtin_amdgcn_readfirstlane(es.y);
        const f32x4 ef0 = *(const f32x4*)(efeat + (long)e * NEFEAT);
        const f32x4 ef1 = *(const f32x4*)(efeat + (long)e * NEFEAT + 4);
        const f32x4 ef2 = *(const f32x4*)(efeat + (long)e * NEFEAT + 8);
        const short4v pv = *(const short4v*)((const short*)P + (long)sN * LDA + vlane * 4);
        const f32x4 q = qcalc(wef, ef0, ef1, ef2);
        f32x4 he;
        #pragma unroll
        for (int u = 0; u < 4; u++) he[u] = lrelu_f(bfbits2f(pv[u]) + q[u]);
        float dot = he[0] * w2[0] + he[1] * w2[1] + he[2] * w2[2] + he[3] * w2[3];
        if (lane >= 50) dot = 0.f;
        #pragma unroll
        for (int off = 32; off > 0; off >>= 1) dot += __shfl_xor(dot, off, 64);
        const float l = lrelu_f(dot + s1b);          // wave-uniform logit
        if (l <= m) {
            const float wgt = __expf(l - m);
            ssum += wgt;
            #pragma unroll
            for (int u = 0; u < 4; u++) a[u] += wgt * he[u];
        } else {
            const float scale = __expf(m - l);       // first iter: exp(-inf)=0
            ssum = ssum * scale + 1.f;
            #pragma unroll
            for (int u = 0; u < 4; u++) a[u] = a[u] * scale + he[u];
            m = l;
        }
    }
    const float inv = __builtin_amdgcn_rcpf(ssum);
    if (lane < 50) {
        short4v o;
        #pragma unroll
        for (int u = 0; u < 4; u++) o[u] = f2bf(a[u] * inv);
        *(short4v*)((short*)hbar + (long)v * LDA + lane * 4) = o;
    }
}

// ---------------------------------------------------------------------------
// GNN softmax+agg: wave per node, single chunked pass with online rescale.
// int2 perm: chunk setup is one coalesced 8B load (no dependent src gather).
// ---------------------------------------------------------------------------
__global__ __launch_bounds__(256)
void gnn_fused_agg_kernel(const __hip_bfloat16* __restrict__ X,
                          const int2* __restrict__ perm,
                          const int* __restrict__ rp,
                          const float* __restrict__ s1, const float* __restrict__ s2,
                          const float* __restrict__ bias,
                          __hip_bfloat16* __restrict__ out)
{
    const int tid = threadIdx.x;
    const int w = tid >> 6, lane = tid & 63;
    const int vlane = (lane < 50) ? lane : 0;
    const int v = __builtin_amdgcn_readfirstlane(blockIdx.x * 4 + w);
    if (v >= V_N) return;
    const int b = __builtin_amdgcn_readfirstlane(rp[v]);
    const int en = __builtin_amdgcn_readfirstlane(rp[v + 1]);
    if (en == b) {
        if (lane < 50) {
            short4v z = {};
            *(short4v*)((short*)out + (long)v * LDA + lane * 4) = z;
        }
        return;
    }
    const float s1v = s1[v] + bias[0];
    float m = -INFINITY, ssum = 0.f;
    f32x4 a = {};
    for (int cb0 = b; cb0 < en; cb0 += 64) {
        int i = cb0 + lane;
        int sL = 0;
        float lv = -INFINITY;
        if (i < en) {
            sL = perm[i].y;                 // coalesced 8B load, no src gather
            lv = lrelu_f(s1v + s2[sL]);
        }
        // chunk max
        float cm = lv;
        #pragma unroll
        for (int off = 32; off > 0; off >>= 1) cm = fmaxf(cm, __shfl_xor(cm, off, 64));
        const float m_new = fmaxf(m, cm);
        const float scale = __expf(m - m_new);   // first chunk: exp(-inf)=0
        ssum *= scale;
        #pragma unroll
        for (int u = 0; u < 4; u++) a[u] *= scale;
        float wgt = (i < en) ? __expf(lv - m_new) : 0.f;
        float ws = wgt;
        #pragma unroll
        for (int off = 32; off > 0; off >>= 1) ws += __shfl_xor(ws, off, 64);
        ssum += ws;
        const int cnt = min(64, en - cb0);
        // gather loop with prefetch
        int sT = __shfl(sL, 0, 64);
        float wT = __shfl(wgt, 0, 64);
        short4v pv = *(const short4v*)((const short*)X + (long)sT * LDA + vlane * 4);
        for (int t = 0; t < cnt; t++) {
            short4v npv;
            float wN;
            if (t + 1 < cnt) {
                int sN = __shfl(sL, t + 1, 64);
                wN = __shfl(wgt, t + 1, 64);
                npv = *(const short4v*)((const short*)X + (long)sN * LDA + vlane * 4);
            }
            #pragma unroll
            for (int u = 0; u < 4; u++)
                a[u] += wT * bfbits2f(pv[u]);
            if (t + 1 < cnt) { pv = npv; wT = wN; }
        }
        m = m_new;
    }
    const float inv = __builtin_amdgcn_rcpf(ssum);
    if (lane < 50) {
        short4v o;
        #pragma unroll
        for (int u = 0; u < 4; u++) o[u] = f2bf(elu_f(a[u] * inv));
        *(short4v*)((short*)out + (long)v * LDA + lane * 4) = o;
    }
}

// ---------------------------------------------------------------------------
// readout
// ---------------------------------------------------------------------------
__global__ __launch_bounds__(256)
void mask_kernel(const float* __restrict__ nfeat, float* __restrict__ mask)
{
    int v = blockIdx.x * blockDim.x + threadIdx.x;
    if (v >= V_N) return;
    const float* row = nfeat + (long)v * NFEAT;
    float s = row[NFEAT - 4] + row[NFEAT - 3] + row[NFEAT - 2] + row[NFEAT - 1];
    float m = s * (1.f - row[0]);
    mask[v] = 1.f / m - 1.f;
}

__global__ __launch_bounds__(256)
void readout_kernel(const __hip_bfloat16* __restrict__ nf, const float* __restrict__ predW,
                    const float* __restrict__ predb, const float* __restrict__ mask,
                    const int* __restrict__ gid, float* __restrict__ out_atom,
                    float* __restrict__ gsum)
{
    int gtid = blockIdx.x * blockDim.x + threadIdx.x;
    int v = gtid >> 6, lane = gtid & 63;
    if (v >= V_N) return;
    int vlane = (lane < 50) ? lane : 0;
    short4v pv = *(const short4v*)((const short*)nf + (long)v * LDA + vlane * 4);
    f32x4 wv = *(const f32x4*)(predW + vlane * 4);
    float acc = 0.f;
    #pragma unroll
    for (int u = 0; u < 4; u++) acc += bfbits2f(pv[u]) * wv[u];
    if (lane >= 50) acc = 0.f;
    for (int off = 32; off > 0; off >>= 1) acc += __shfl_down(acc, off, 64);
    if (lane == 0) {
        float p = acc + predb[0] + mask[v];
        out_atom[v] = p;
        atomicAdd(&gsum[gid[v]], exp10f(-p));
    }
}

__global__ __launch_bounds__(256)
void graph_out_kernel(const float* __restrict__ gsum, float* __restrict__ out_g)
{
    int g = blockIdx.x * blockDim.x + threadIdx.x;
    if (g >= NG_N) return;
    out_g[g] = -log10f(gsum[g]);
}

// ---------------------------------------------------------------------------
extern "C" void kernel_launch(void* const* d_in, const int* in_sizes, int n_in,
                              void* d_out, int out_size, void* d_ws, size_t ws_size,
                              hipStream_t stream)
{
    const float* node_feats = (const float*)d_in[0];
    const float* edge_feats = (const float*)d_in[1];
    const float* pn_W  = (const float*)d_in[2];
    const float* pn_b  = (const float*)d_in[3];
    const float* pe1_W = (const float*)d_in[4];
    const float* pe1_b = (const float*)d_in[5];
    const float* pe2_W = (const float*)d_in[6];
    const float* pe2_b = (const float*)d_in[7];
    const float* et_W  = (const float*)d_in[8];
    const float* et_b  = (const float*)d_in[9];
    const float* gru0_Wih = (const float*)d_in[10];
    const float* gru0_Whh = (const float*)d_in[11];
    const float* gru0_bih = (const float*)d_in[12];
    const float* gru0_bhh = (const float*)d_in[13];
    const float* gnn_pe_W = (const float*)d_in[14];
    const float* gnn_pe_b = (const float*)d_in[15];
    const float* gnn_pn_W = (const float*)d_in[16];
    const float* gnn_pn_b = (const float*)d_in[17];
    const float* gnn_gru_Wih = (const float*)d_in[18];
    const float* gnn_gru_Whh = (const float*)d_in[19];
    const float* gnn_gru_bih = (const float*)d_in[20];
    const float* gnn_gru_bhh = (const float*)d_in[21];
    const float* pred_W = (const float*)d_in[22];
    const float* pred_b = (const float*)d_in[23];
    const int* src = (const int*)d_in[24];
    const int* dst = (const int*)d_in[25];
    const int* gid = (const int*)d_in[26];

    float* out_g = (float*)d_out;
    float* out_atom = out_g + NG_N;

    char* base = (char*)d_ws;
    size_t off = 0;
    auto take = [&](size_t bytes) -> void* {
        void* p = base + off;
        off += (bytes + 255) & ~(size_t)255;
        return p;
    };
    const size_t VP = (size_t)V_N * LDA;
    const size_t WPL = (size_t)14 * 14 * 1536;   // = 301056
    float* mask   = (float*)take((size_t)V_N * 4);
    float* s1     = (float*)take((size_t)V_N * 4);
    float* s2     = (float*)take((size_t)V_N * 4);
    float* gsum   = (float*)take((size_t)NG_N * 4);
    __hip_bfloat16* c    = (__hip_bfloat16*)take(VP * 2);
    __hip_bfloat16* hv   = (__hip_bfloat16*)take(VP * 2);
    __hip_bfloat16* nf_a = (__hip_bfloat16*)take(VP * 2);
    __hip_bfloat16* nf_b = (__hip_bfloat16*)take(VP * 2);
    short* WpGru = (short*)take(3 * WPL * 2);
    short* Wp_pn0 = (short*)take((size_t)256 * 96 * 2);
    short* Wp_pe1 = (short*)take((size_t)256 * 96 * 2);
    short* Wp_et  = (short*)take((size_t)7 * 7 * 1024 * 2);
    short* Wp_pn1 = (short*)take((size_t)7 * 7 * 1024 * 2);
    short* Wp_pn2 = (short*)take((size_t)7 * 7 * 1024 * 2);
    int* deg  = (int*)take((size_t)V_N * 4);
    int* cnt  = (int*)take((size_t)V_N * 4);
    int* rp   = (int*)take((size_t)(V_N + 1) * 4);
    int2* perm = (int2*)take((size_t)E_N * 8);
    int* bsum = (int*)take((size_t)512 * 4);
    __hip_bfloat16* P    = nf_a;  // alias: nf_a written only at GRU0
    __hip_bfloat16* hbar = nf_b;  // alias: nf_b first written as layer-0 GRU output
    __hip_bfloat16* hvp  = hv;    // alias: hv dead after GRU0

    if (off > ws_size) {
        fill_kernel<<<cdiv(out_size, 256), 256, 0, stream>>>((float*)d_out, -12345.f, out_size);
        return;
    }

    const int BLK = 256;
    const int nScanBlocks = cdiv(V_N, 256);
    const dim3 gOld(4, cdiv(V_N, 64));
    const int gAgg = cdiv(V_N, 4);

    // zero only the pad columns of the 4 contiguous node matrices
    pad_zero_kernel<<<cdiv(4 * V_N, BLK), BLK, 0, stream>>>((short*)c, VP);

    // ---- weight prep ----
    gru_wprep_kernel<<<cdiv(14 * 14 * 1536, 256), BLK, 0, stream>>>(gru0_Wih, gru0_Whh, WpGru);
    for (int l = 0; l < L_N; l++)
        gru_wprep_kernel<<<cdiv(14 * 14 * 1536, 256), BLK, 0, stream>>>(
            gnn_gru_Wih + (size_t)l * G_DIM * 3 * G_DIM,
            gnn_gru_Whh + (size_t)l * G_DIM * 3 * G_DIM,
            WpGru + (size_t)(l + 1) * WPL);
    wprep_kernel<<<cdiv(256 * 96, 256), BLK, 0, stream>>>(pn_W, Wp_pn0, NFEAT, 96);
    wprep_kernel<<<cdiv(256 * 96, 256), BLK, 0, stream>>>(pe1_W, Wp_pe1, NFEAT, 96);
    wprep_tiled_kernel<<<cdiv(7 * 7 * 1024, 256), BLK, 0, stream>>>(et_W, Wp_et);
    wprep_tiled_kernel<<<cdiv(7 * 7 * 1024, 256), BLK, 0, stream>>>(gnn_pn_W, Wp_pn1);
    wprep_tiled_kernel<<<cdiv(7 * 7 * 1024, 256), BLK, 0, stream>>>(
        gnn_pn_W + (size_t)G_DIM * G_DIM, Wp_pn2);

    mask_kernel<<<cdiv(V_N, BLK), BLK, 0, stream>>>(node_feats, mask);

    // ---- CSR build (by dst) ----
    fill_int_kernel<<<cdiv(V_N, BLK), BLK, 0, stream>>>(deg, 0, V_N);
    hist_kernel<<<cdiv(E_N, BLK), BLK, 0, stream>>>(dst, deg);
    scan1_kernel<<<nScanBlocks, BLK, 0, stream>>>(deg, rp, bsum);
    scan2_kernel<<<1, 1, 0, stream>>>(bsum, rp, nScanBlocks);
    scan3_kernel<<<nScanBlocks, BLK, 0, stream>>>(rp, bsum);
    fill_int_kernel<<<cdiv(V_N, BLK), BLK, 0, stream>>>(cnt, 0, V_N);
    csr_fill_kernel<<<cdiv(E_N, BLK), BLK, 0, stream>>>(dst, src, rp, cnt, perm);

    // ---- GetContext ----
    gemm_f32a_dual_kernel<<<gOld, BLK, 0, stream>>>(
        node_feats, Wp_pn0, pn_b, Wp_pe1, pe1_b, hv, P);
    node_dot2_kernel<<<gAgg, BLK, 0, stream>>>(hv, pe2_W, nullptr, s1, nullptr);
    ctx_fused_kernel<<<gAgg, BLK, 0, stream>>>(
        P, edge_feats, perm, rp, s1, pe1_W, pe2_W, pe2_b, hbar);
    gemm_bf16a_kernel<3><<<NSWZ, BLK, 0, stream>>>(hbar, Wp_et, et_b, c);
    gru_mfma_kernel<<<NSWZG, BLK, 0, stream>>>(c, hv, WpGru, gru0_bih, gru0_bhh, nf_a);

    // ---- GNN layers ----
    __hip_bfloat16* cur = nf_a;
    __hip_bfloat16* nxt = nf_b;
    for (int l = 0; l < L_N; l++) {
        const float* pe_W = gnn_pe_W + (size_t)l * 2 * G_DIM;
        const float* pe_b = gnn_pe_b + l;
        const float* pnB  = gnn_pn_b + (size_t)l * G_DIM;
        const float* bih  = gnn_gru_bih + (size_t)l * 3 * G_DIM;
        const float* bhh  = gnn_gru_bhh + (size_t)l * 3 * G_DIM;
        const short* WpPn = (l == 0) ? Wp_pn1 : Wp_pn2;

        node_dot2_kernel<<<gAgg, BLK, 0, stream>>>(cur, pe_W, pe_W + G_DIM, s1, s2);
        gemm_bf16a_kernel<1><<<NSWZ, BLK, 0, stream>>>(cur, WpPn, pnB, hvp);
        gnn_fused_agg_kernel<<<gAgg, BLK, 0, stream>>>(
            hvp, perm, rp, s1, s2, pe_b, c);
        gru_mfma_kernel<<<NSWZG, BLK, 0, stream>>>(
            c, cur, WpGru + (size_t)(l + 1) * WPL, bih, bhh, nxt);

        __hip_bfloat16* tmp = cur; cur = nxt; nxt = tmp;
    }

    // ---- readout ----
    fill_kernel<<<cdiv(NG_N, BLK), BLK, 0, stream>>>(gsum, 0.f, NG_N);
    readout_kernel<<<cdiv(V_N * 64, BLK), BLK, 0, stream>>>(
        cur, pred_W, pred_b, mask, gid, out_atom, gsum);
    graph_out_kernel<<<cdiv(NG_N, BLK), BLK, 0, stream>>>(gsum, out_g);
}